// Round 1
// 732.110 us; speedup vs baseline: 1.2050x; 1.2050x over previous
//
#include <hip/hip_runtime.h>
#include <math.h>

#define NBASE 100000
#define DIM   1024
#define NE    8
#define NSUP  128
#define KSEL  15000
#define NB1   4096
#define CAP2  1024

// ---------- helpers ----------
__device__ __forceinline__ float dot4(float4 a, float4 b) {
    return a.x*b.x + a.y*b.y + a.z*b.z + a.w*b.w;
}
__device__ __forceinline__ float4 scale4(float4 a, float s) {
    return make_float4(a.x*s, a.y*s, a.z*s, a.w*s);
}
__device__ __forceinline__ float4 add4(float4 a, float4 b) {
    return make_float4(a.x+b.x, a.y+b.y, a.z+b.z, a.w+b.w);
}
// butterfly: all lanes end with the full 64-lane sum
__device__ __forceinline__ float wave_sum_xor(float v) {
    #pragma unroll
    for (int m = 1; m < 64; m <<= 1) v += __shfl_xor(v, m, 64);
    return v;
}
__device__ __forceinline__ float wave_sum(float v) {
    #pragma unroll
    for (int off = 32; off > 0; off >>= 1) v += __shfl_down(v, off, 64);
    return v;
}
__device__ __forceinline__ float block_sum(float v, float* red) {
    int lane = threadIdx.x & 63, wv = threadIdx.x >> 6;
    v = wave_sum(v);
    __syncthreads();
    if (lane == 0) red[wv] = v;
    __syncthreads();
    return red[0] + red[1] + red[2] + red[3];
}
// identical binning in every kernel (bit-identical codegen)
__device__ __forceinline__ int bin1(float s) {
    int b = (int)((s + 1.0001f) * ((float)NB1 / 2.0002f));
    return min(max(b, 0), NB1 - 1);
}
__device__ __forceinline__ int bin2(float s, int B) {
    float lo2 = -1.0001f + (float)B * (2.0002f / (float)NB1);
    int b = (int)((s - lo2) * ((float)NB1 / 2.0002f * 256.0f));
    return min(max(b, 0), 255);
}

// ---------- K1a: normalize each support row, partial-sum per (e, group of 4 rows) ----------
// grid 256 = NE*32, one row per wave
__global__ void k1a(const float* __restrict__ F, float* __restrict__ Qpart) {
    int blk = blockIdx.x;
    int e = blk >> 5, g = blk & 31;
    int wv = threadIdx.x >> 6, lane = threadIdx.x & 63;
    int r = g * 4 + wv;
    const float4* row = (const float4*)(F + ((size_t)e * 1024 + r) * DIM);
    float4 f0 = row[lane], f1 = row[64+lane], f2 = row[128+lane], f3 = row[192+lane];
    float ss = dot4(f0,f0) + dot4(f1,f1) + dot4(f2,f2) + dot4(f3,f3);
    ss = wave_sum_xor(ss);
    float inv = 1.f / fmaxf(sqrtf(ss), 1e-12f);
    __shared__ float part[4][1024];
    float4* p4 = (float4*)part[wv];
    p4[lane]     = scale4(f0, inv);
    p4[64+lane]  = scale4(f1, inv);
    p4[128+lane] = scale4(f2, inv);
    p4[192+lane] = scale4(f3, inv);
    __syncthreads();
    int tid = threadIdx.x;
    const float4* pp = (const float4*)part;
    float4 s = add4(add4(pp[tid], pp[256+tid]), add4(pp[512+tid], pp[768+tid]));
    ((float4*)Qpart)[(size_t)(e*32+g)*256 + tid] = s;
}

// ---------- K1b: combine 32 partials per e, normalize -> Q ----------
__global__ void k1b(const float* __restrict__ Qpart, float* __restrict__ Q) {
    int e = blockIdx.x, tid = threadIdx.x;
    __shared__ float red[4];
    const float4* qp = (const float4*)Qpart;
    float4 s = make_float4(0.f,0.f,0.f,0.f);
    #pragma unroll 4
    for (int g = 0; g < 32; ++g) s = add4(s, qp[(size_t)(e*32+g)*256 + tid]);
    float ss = block_sum(dot4(s,s), red);
    float inv = 1.f / fmaxf(sqrtf(ss), 1e-12f);
    ((float4*)Q)[e*256 + tid] = scale4(s, inv);
}

// ---------- K2: wave-per-row sims; writes S[i][e], S_T[e][i], InvN[i] ----------
// grid 25000 blocks, 4 waves = 4 rows per block
__global__ void k2_sim(const float* __restrict__ Bse, const float* __restrict__ Q,
                       float* __restrict__ S, float* __restrict__ ST,
                       float* __restrict__ InvN) {
    __shared__ float q_sh[NE * DIM];   // 32 KB
    int tid = threadIdx.x, wv = tid >> 6, lane = tid & 63;
    {
        const float4* Q4 = (const float4*)Q;
        float4* q4 = (float4*)q_sh;
        #pragma unroll
        for (int k = 0; k < 8; ++k) q4[k*256 + tid] = Q4[k*256 + tid];
    }
    __syncthreads();
    const float4* q4 = (const float4*)q_sh;
    size_t i = (size_t)blockIdx.x * 4 + wv;
    const float4* b4 = (const float4*)(Bse + i * DIM);
    float4 b0 = b4[lane], b1 = b4[64+lane], b2 = b4[128+lane], b3 = b4[192+lane];
    float pv[9];
    pv[8] = dot4(b0,b0) + dot4(b1,b1) + dot4(b2,b2) + dot4(b3,b3);
    #pragma unroll
    for (int e = 0; e < NE; ++e) {
        float4 q0 = q4[e*256+lane],     q1 = q4[e*256+64+lane];
        float4 q2 = q4[e*256+128+lane], q3 = q4[e*256+192+lane];
        pv[e] = dot4(b0,q0) + dot4(b1,q1) + dot4(b2,q2) + dot4(b3,q3);
    }
    #pragma unroll
    for (int v = 0; v < 9; ++v) pv[v] = wave_sum_xor(pv[v]);
    float invn = 1.f / fmaxf(sqrtf(pv[8]), 1e-12f);
    if (lane < 8) {
        float v = pv[0];
        #pragma unroll
        for (int e = 1; e < 8; ++e) v = (lane == e) ? pv[e] : v;
        float sv = v * invn;
        S[i*NE + lane] = sv;
        ST[(size_t)lane*NBASE + i] = sv;
    }
    if (lane == 0) InvN[i] = invn;
}

// ---------- K3a: per-e 4096-bin histogram (parallel, coalesced over S_T) ----------
// grid 256 = NE*32
__global__ void k3a(const float* __restrict__ ST, int* __restrict__ Hist) {
    int e = blockIdx.x >> 5, chunk = blockIdx.x & 31;
    __shared__ int h[NB1];
    for (int b = threadIdx.x; b < NB1; b += 256) h[b] = 0;
    __syncthreads();
    const int per = (NBASE + 31) / 32;
    int i0 = chunk * per, i1 = min(i0 + per, NBASE);
    for (int i = i0 + threadIdx.x; i < i1; i += 256) {
        float s = ST[(size_t)e*NBASE + i];
        atomicAdd(&h[bin1(s)], 1);
    }
    __syncthreads();
    for (int b = threadIdx.x; b < NB1; b += 256)
        if (h[b]) atomicAdd(&Hist[e*NB1 + b], h[b]);
}

// ---------- K3b: find boundary bin B and need1 per e ----------
__global__ void k3b(const int* __restrict__ Hist, int* __restrict__ Meta) {
    int e = blockIdx.x, tid = threadIdx.x;
    __shared__ int gsum[256];
    int s = 0;
    #pragma unroll
    for (int j = 0; j < 16; ++j) s += Hist[e*NB1 + tid*16 + j];
    gsum[tid] = s;
    __syncthreads();
    if (tid == 0) {
        int cum = 0;
        for (int g = 255; g >= 0; --g) {
            if (cum + gsum[g] >= KSEL) {
                for (int b = g*16 + 15;; --b) {
                    int c = Hist[e*NB1 + b];
                    if (cum + c >= KSEL) { Meta[e*4+0] = b; Meta[e*4+1] = KSEL - cum; break; }
                    cum += c;
                }
                break;
            }
            cum += gsum[g];
        }
    }
}

// ---------- K3c: 256-sub-bin histogram of boundary bin ----------
__global__ void k3c(const float* __restrict__ ST, const int* __restrict__ Meta,
                    int* __restrict__ SubHist) {
    int e = blockIdx.x >> 5, chunk = blockIdx.x & 31;
    int B = Meta[e*4];
    __shared__ int h[256];
    h[threadIdx.x] = 0;
    __syncthreads();
    const int per = (NBASE + 31) / 32;
    int i0 = chunk * per, i1 = min(i0 + per, NBASE);
    for (int i = i0 + threadIdx.x; i < i1; i += 256) {
        float s = ST[(size_t)e*NBASE + i];
        if (bin1(s) == B) atomicAdd(&h[bin2(s, B)], 1);
    }
    __syncthreads();
    if (h[threadIdx.x]) atomicAdd(&SubHist[e*256 + threadIdx.x], h[threadIdx.x]);
}

// ---------- K3d: find sub-bin B2 and need2 per e ----------
__global__ void k3d(const int* __restrict__ SubHist, int* __restrict__ Meta) {
    int e = blockIdx.x;
    if (threadIdx.x != 0) return;
    int need1 = Meta[e*4+1], cum = 0;
    for (int b = 255; b >= 0; --b) {
        int c = SubHist[e*256 + b];
        if (cum + c >= need1) { Meta[e*4+2] = b; Meta[e*4+3] = need1 - cum; return; }
        cum += c;
    }
    Meta[e*4+2] = 0; Meta[e*4+3] = need1 - cum;
}

// ---------- K3e: flags pass (1 thread per row, all 8 e) + boundary candidates ----------
__global__ void k3e(const float* __restrict__ S, const int* __restrict__ Meta,
                    unsigned char* __restrict__ Flags, int* __restrict__ CandI,
                    float* __restrict__ CandV, int* __restrict__ CandCnt) {
    int i = blockIdx.x * 256 + threadIdx.x;
    if (i >= NBASE) return;
    const float4* S4 = (const float4*)S;
    float4 sa = S4[(size_t)i*2], sb = S4[(size_t)i*2 + 1];
    float sv[8] = {sa.x, sa.y, sa.z, sa.w, sb.x, sb.y, sb.z, sb.w};
    unsigned long long flw = 0ull;
    #pragma unroll
    for (int e = 0; e < 8; ++e) {
        int B = Meta[e*4], B2 = Meta[e*4+2];
        int b = bin1(sv[e]);
        int fl = 0;
        if (b > B) fl = 1;
        else if (b == B) {
            int b2 = bin2(sv[e], B);
            if (b2 > B2) fl = 1;
            else if (b2 == B2) {
                int k = atomicAdd(&CandCnt[e], 1);
                if (k < CAP2) { CandI[e*CAP2 + k] = i; CandV[e*CAP2 + k] = sv[e]; }
            }
        }
        flw |= ((unsigned long long)fl) << (8*e);
    }
    *(unsigned long long*)(Flags + (size_t)i * 8) = flw;
}

// ---------- K3f: pick need2 winners in boundary sub-bin (value desc, idx asc) ----------
__global__ void k3f(const int* __restrict__ Meta, const int* __restrict__ CandCnt,
                    int* __restrict__ CandI, const float* __restrict__ CandV,
                    unsigned char* __restrict__ Flags) {
    int e = blockIdx.x;
    if (threadIdx.x != 0) return;
    int need2 = Meta[e*4+3];
    int n = min(CandCnt[e], CAP2);
    for (int t = 0; t < need2; ++t) {
        int best = -1, bi = 0; float bv = 0.f;
        for (int j = 0; j < n; ++j) {
            int ij = CandI[e*CAP2 + j];
            if (ij < 0) continue;
            float vj = CandV[e*CAP2 + j];
            if (best < 0 || vj > bv || (vj == bv && ij < bi)) { best = j; bv = vj; bi = ij; }
        }
        if (best < 0) break;
        Flags[(size_t)bi * NE + e] = 1;
        CandI[e*CAP2 + best] = -1;
    }
}

// ---------- K3g: compact selected rows -> (SelIdx, Coef[8]) list ----------
// One thread per row. Wave-level ballot + prefix, one atomicAdd per wave.
__global__ void k3g(const float* __restrict__ S, const float* __restrict__ InvN,
                    const unsigned char* __restrict__ Flags,
                    int* __restrict__ SelIdx, float* __restrict__ Coef,
                    int* __restrict__ SelCnt) {
    int i = blockIdx.x * 256 + threadIdx.x;
    int lane = threadIdx.x & 63;
    unsigned long long fl = 0ull;
    bool act = false;
    if (i < NBASE) {
        fl = *(const unsigned long long*)(Flags + (size_t)i * 8);
        act = (fl != 0ull);
    }
    unsigned long long ball = __ballot(act);
    int total = __popcll(ball);
    int prefix = __popcll(ball & ((1ull << lane) - 1ull));
    int base = 0;
    if (lane == 0 && total) base = atomicAdd(SelCnt, total);
    base = __shfl(base, 0, 64);
    if (act) {
        int slot = base + prefix;
        SelIdx[slot] = i;
        float inv = InvN[i];
        const float4* S4 = (const float4*)S;
        float4 sa = S4[(size_t)i*2], sb = S4[(size_t)i*2 + 1];
        float sv[8] = {sa.x, sa.y, sa.z, sa.w, sb.x, sb.y, sb.z, sb.w};
        float cf[8];
        #pragma unroll
        for (int e = 0; e < 8; ++e)
            cf[e] = ((fl >> (8*e)) & 0xffull) ? sqrtf(fmaxf(sv[e], 0.f)) * inv : 0.f;
        float4* C4 = (float4*)(Coef + (size_t)slot * 8);
        C4[0] = make_float4(cf[0], cf[1], cf[2], cf[3]);
        C4[1] = make_float4(cf[4], cf[5], cf[6], cf[7]);
    }
}

// ---------- K4: weighted accumulate over COMPACTED list -> per-block partials ----------
// Branch-free inner loop; next-index prefetch breaks the idx->row load chain.
__global__ void k4_part(const float* __restrict__ Bse, const int* __restrict__ SelIdx,
                        const float* __restrict__ Coef, const int* __restrict__ SelCnt,
                        float* __restrict__ Part) {
    int tid = threadIdx.x;
    int n = *SelCnt;
    int G = gridDim.x;
    float acc[NE][4];
    #pragma unroll
    for (int e = 0; e < NE; ++e)
        #pragma unroll
        for (int j = 0; j < 4; ++j) acc[e][j] = 0.f;
    int j = blockIdx.x;
    int idx = (j < n) ? SelIdx[j] : 0;
    for (; j < n; j += G) {
        int jn = j + G;
        int nidx = (jn < n) ? SelIdx[jn] : 0;     // prefetch next index
        const float4* cf4 = (const float4*)(Coef + (size_t)j * 8);
        float4 c0 = cf4[0], c1 = cf4[1];
        float cf[8] = {c0.x, c0.y, c0.z, c0.w, c1.x, c1.y, c1.z, c1.w};
        float4 b = ((const float4*)(Bse + (size_t)idx * DIM))[tid];
        #pragma unroll
        for (int e = 0; e < NE; ++e) {
            acc[e][0] += cf[e] * b.x;
            acc[e][1] += cf[e] * b.y;
            acc[e][2] += cf[e] * b.z;
            acc[e][3] += cf[e] * b.w;
        }
        idx = nidx;
    }
    float4* P4 = (float4*)Part;
    #pragma unroll
    for (int e = 0; e < NE; ++e)
        P4[(size_t)blockIdx.x*2048 + e*256 + tid] =
            make_float4(acc[e][0], acc[e][1], acc[e][2], acc[e][3]);
}

// fallback when ws is too small for partials
__global__ void k4_atomic(const float* __restrict__ Bse, const int* __restrict__ SelIdx,
                          const float* __restrict__ Coef, const int* __restrict__ SelCnt,
                          float* __restrict__ Acc) {
    int tid = threadIdx.x;
    int n = *SelCnt;
    int G = gridDim.x;
    float acc[NE][4];
    #pragma unroll
    for (int e = 0; e < NE; ++e)
        #pragma unroll
        for (int j = 0; j < 4; ++j) acc[e][j] = 0.f;
    int j = blockIdx.x;
    int idx = (j < n) ? SelIdx[j] : 0;
    for (; j < n; j += G) {
        int jn = j + G;
        int nidx = (jn < n) ? SelIdx[jn] : 0;
        const float4* cf4 = (const float4*)(Coef + (size_t)j * 8);
        float4 c0 = cf4[0], c1 = cf4[1];
        float cf[8] = {c0.x, c0.y, c0.z, c0.w, c1.x, c1.y, c1.z, c1.w};
        float4 b = ((const float4*)(Bse + (size_t)idx * DIM))[tid];
        #pragma unroll
        for (int e = 0; e < NE; ++e) {
            acc[e][0] += cf[e] * b.x;
            acc[e][1] += cf[e] * b.y;
            acc[e][2] += cf[e] * b.z;
            acc[e][3] += cf[e] * b.w;
        }
        idx = nidx;
    }
    #pragma unroll
    for (int e = 0; e < NE; ++e)
        #pragma unroll
        for (int q = 0; q < 4; ++q)
            atomicAdd(&Acc[e*DIM + tid*4 + q], acc[e][q]);
}

// ---------- K4b: reduce partials (32 slices per output chunk) ----------
__global__ void k4b(const float* __restrict__ Part, float* __restrict__ Acc, int nparts) {
    int g = blockIdx.x * 256 + threadIdx.x;   // 65536 threads
    int c = g & 2047, s = g >> 11;            // 32 slices
    const float4* P4 = (const float4*)Part;
    float4 a = make_float4(0.f,0.f,0.f,0.f);
    for (int b = s; b < nparts; b += 32) a = add4(a, P4[(size_t)b*2048 + c]);
    atomicAdd(&Acc[c*4+0], a.x);
    atomicAdd(&Acc[c*4+1], a.y);
    atomicAdd(&Acc[c*4+2], a.z);
    atomicAdd(&Acc[c*4+3], a.w);
}

// ---------- K5: A = normalize(Acc) ----------
__global__ void k5(const float* __restrict__ Acc, float* __restrict__ A) {
    int e = blockIdx.x, tid = threadIdx.x;
    __shared__ float red[4];
    float4 a = ((const float4*)Acc)[e*256 + tid];
    float ss = block_sum(dot4(a,a), red);
    float inv = 1.f / fmaxf(sqrtf(ss), 1e-12f);
    ((float4*)A)[e*256 + tid] = scale4(a, inv);
}

// ---------- K6: out = normalize(fn - (fn.a) a), wave-per-row ----------
__global__ void k6(const float* __restrict__ F, const float* __restrict__ A,
                   float* __restrict__ Out) {
    int wv = threadIdx.x >> 6, lane = threadIdx.x & 63;
    size_t rid = (size_t)blockIdx.x * 4 + wv;
    int e = (int)(rid >> 10);
    const float4* f4 = (const float4*)(F + rid * DIM);
    const float4* a4 = (const float4*)(A + (size_t)e * DIM);
    float4 f0 = f4[lane], f1 = f4[64+lane], f2 = f4[128+lane], f3 = f4[192+lane];
    float4 a0 = a4[lane], a1 = a4[64+lane], a2 = a4[128+lane], a3 = a4[192+lane];
    float ss = dot4(f0,f0) + dot4(f1,f1) + dot4(f2,f2) + dot4(f3,f3);
    ss = wave_sum_xor(ss);
    float invf = 1.f / fmaxf(sqrtf(ss), 1e-12f);
    f0 = scale4(f0, invf); f1 = scale4(f1, invf); f2 = scale4(f2, invf); f3 = scale4(f3, invf);
    float c = dot4(f0,a0) + dot4(f1,a1) + dot4(f2,a2) + dot4(f3,a3);
    c = wave_sum_xor(c);
    float4 r0 = make_float4(f0.x - c*a0.x, f0.y - c*a0.y, f0.z - c*a0.z, f0.w - c*a0.w);
    float4 r1 = make_float4(f1.x - c*a1.x, f1.y - c*a1.y, f1.z - c*a1.z, f1.w - c*a1.w);
    float4 r2 = make_float4(f2.x - c*a2.x, f2.y - c*a2.y, f2.z - c*a2.z, f2.w - c*a2.w);
    float4 r3 = make_float4(f3.x - c*a3.x, f3.y - c*a3.y, f3.z - c*a3.z, f3.w - c*a3.w);
    float rs = dot4(r0,r0) + dot4(r1,r1) + dot4(r2,r2) + dot4(r3,r3);
    rs = wave_sum_xor(rs);
    float invr = 1.f / fmaxf(sqrtf(rs), 1e-12f);
    float4* o4 = (float4*)(Out + rid * DIM);
    o4[lane]     = scale4(r0, invr);
    o4[64+lane]  = scale4(r1, invr);
    o4[128+lane] = scale4(r2, invr);
    o4[192+lane] = scale4(r3, invr);
}

extern "C" void kernel_launch(void* const* d_in, const int* in_sizes, int n_in,
                              void* d_out, int out_size, void* d_ws, size_t ws_size,
                              hipStream_t stream) {
    const float* F   = (const float*)d_in[0];   // (8,1024,1024)
    const float* Bse = (const float*)d_in[1];   // (100000,1024)
    float* Out = (float*)d_out;

    char* ws = (char*)d_ws;
    size_t off = 0;
    auto alloc = [&](size_t bytes) -> void* {
        void* p = ws + off;
        off += (bytes + 255) & ~(size_t)255;
        return p;
    };
    float* Q     = (float*)alloc((size_t)NE * DIM * 4);
    float* Qpart = (float*)alloc((size_t)NE * 32 * DIM * 4);       // 1 MB
    float* S     = (float*)alloc((size_t)NBASE * NE * 4);          // 3.2 MB
    float* ST    = (float*)alloc((size_t)NE * NBASE * 4);          // 3.2 MB
    float* InvN  = (float*)alloc((size_t)NBASE * 4);               // 0.4 MB
    unsigned char* Flags = (unsigned char*)alloc((size_t)NBASE * NE); // 0.8 MB
    int*   Zero  = (int*)alloc((size_t)(NE*NB1 + NE*256 + NE + 1) * 4); // Hist+SubHist+CandCnt+SelCnt
    int*   Hist    = Zero;
    int*   SubHist = Zero + NE*NB1;
    int*   CandCnt = Zero + NE*NB1 + NE*256;
    int*   SelCnt  = Zero + NE*NB1 + NE*256 + NE;
    int*   Meta  = (int*)alloc((size_t)NE * 4 * 4);
    int*   CandI = (int*)alloc((size_t)NE * CAP2 * 4);
    float* CandV = (float*)alloc((size_t)NE * CAP2 * 4);
    float* Acc   = (float*)alloc((size_t)NE * DIM * 4);
    float* A     = (float*)alloc((size_t)NE * DIM * 4);
    int*   SelIdx = (int*)alloc((size_t)NBASE * 4);                // 0.4 MB
    float* Coef   = (float*)alloc((size_t)NBASE * 8 * 4);          // 3.2 MB

    // Part buffer sized by remaining workspace; prefer a big grid for occupancy
    int nparts = 0;
    float* Part = nullptr;
    size_t perPart = (size_t)NE * DIM * 4;   // 32 KB per block
    for (int cand : {2048, 1024, 512, 256}) {
        if (ws_size >= off + (size_t)cand * perPart) {
            nparts = cand;
            Part = (float*)alloc((size_t)cand * perPart);
            break;
        }
    }

    hipMemsetAsync(Zero, 0, (size_t)(NE*NB1 + NE*256 + NE + 1) * 4, stream);
    hipMemsetAsync(Acc, 0, (size_t)NE * DIM * 4, stream);

    k1a<<<NE*32, 256, 0, stream>>>(F, Qpart);
    k1b<<<NE, 256, 0, stream>>>(Qpart, Q);
    k2_sim<<<(NBASE+3)/4, 256, 0, stream>>>(Bse, Q, S, ST, InvN);
    k3a<<<NE*32, 256, 0, stream>>>(ST, Hist);
    k3b<<<NE, 256, 0, stream>>>(Hist, Meta);
    k3c<<<NE*32, 256, 0, stream>>>(ST, Meta, SubHist);
    k3d<<<NE, 64, 0, stream>>>(SubHist, Meta);
    k3e<<<(NBASE+255)/256, 256, 0, stream>>>(S, Meta, Flags, CandI, CandV, CandCnt);
    k3f<<<NE, 64, 0, stream>>>(Meta, CandCnt, CandI, CandV, Flags);
    k3g<<<(NBASE+255)/256, 256, 0, stream>>>(S, InvN, Flags, SelIdx, Coef, SelCnt);
    if (nparts) {
        k4_part<<<nparts, 256, 0, stream>>>(Bse, SelIdx, Coef, SelCnt, Part);
        k4b<<<256, 256, 0, stream>>>(Part, Acc, nparts);
    } else {
        k4_atomic<<<512, 256, 0, stream>>>(Bse, SelIdx, Coef, SelCnt, Acc);
    }
    k5<<<NE, 256, 0, stream>>>(Acc, A);
    k6<<<(NE*1024)/4, 256, 0, stream>>>(F, A, Out);
}

// Round 3
// 715.499 us; speedup vs baseline: 1.2330x; 1.0232x over previous
//
#include <hip/hip_runtime.h>
#include <math.h>

#define NBASE 100000
#define DIM   1024
#define NE    8
#define NSUP  128
#define KSEL  15000
#define NB1   4096
#define CAP2  1024

// ---------- helpers ----------
__device__ __forceinline__ float dot4(float4 a, float4 b) {
    return a.x*b.x + a.y*b.y + a.z*b.z + a.w*b.w;
}
__device__ __forceinline__ float4 scale4(float4 a, float s) {
    return make_float4(a.x*s, a.y*s, a.z*s, a.w*s);
}
__device__ __forceinline__ float4 add4(float4 a, float4 b) {
    return make_float4(a.x+b.x, a.y+b.y, a.z+b.z, a.w+b.w);
}
// butterfly: all lanes end with the full 64-lane sum
__device__ __forceinline__ float wave_sum_xor(float v) {
    #pragma unroll
    for (int m = 1; m < 64; m <<= 1) v += __shfl_xor(v, m, 64);
    return v;
}
__device__ __forceinline__ float wave_sum(float v) {
    #pragma unroll
    for (int off = 32; off > 0; off >>= 1) v += __shfl_down(v, off, 64);
    return v;
}
__device__ __forceinline__ float block_sum(float v, float* red) {
    int lane = threadIdx.x & 63, wv = threadIdx.x >> 6;
    v = wave_sum(v);
    __syncthreads();
    if (lane == 0) red[wv] = v;
    __syncthreads();
    return red[0] + red[1] + red[2] + red[3];
}
// identical binning in every kernel (bit-identical codegen)
__device__ __forceinline__ int bin1(float s) {
    int b = (int)((s + 1.0001f) * ((float)NB1 / 2.0002f));
    return min(max(b, 0), NB1 - 1);
}
__device__ __forceinline__ int bin2(float s, int B) {
    float lo2 = -1.0001f + (float)B * (2.0002f / (float)NB1);
    int b = (int)((s - lo2) * ((float)NB1 / 2.0002f * 256.0f));
    return min(max(b, 0), 255);
}
// accumulate one weighted row into acc
__device__ __forceinline__ void fma_row(float acc[NE][4], const float* cf, float4 b) {
    #pragma unroll
    for (int e = 0; e < NE; ++e) {
        acc[e][0] += cf[e] * b.x;
        acc[e][1] += cf[e] * b.y;
        acc[e][2] += cf[e] * b.z;
        acc[e][3] += cf[e] * b.w;
    }
}

// ---------- K1a: normalize each support row, partial-sum per (e, group of 4 rows) ----------
// grid 256 = NE*32, one row per wave
__global__ void k1a(const float* __restrict__ F, float* __restrict__ Qpart) {
    int blk = blockIdx.x;
    int e = blk >> 5, g = blk & 31;
    int wv = threadIdx.x >> 6, lane = threadIdx.x & 63;
    int r = g * 4 + wv;
    const float4* row = (const float4*)(F + ((size_t)e * 1024 + r) * DIM);
    float4 f0 = row[lane], f1 = row[64+lane], f2 = row[128+lane], f3 = row[192+lane];
    float ss = dot4(f0,f0) + dot4(f1,f1) + dot4(f2,f2) + dot4(f3,f3);
    ss = wave_sum_xor(ss);
    float inv = 1.f / fmaxf(sqrtf(ss), 1e-12f);
    __shared__ float part[4][1024];
    float4* p4 = (float4*)part[wv];
    p4[lane]     = scale4(f0, inv);
    p4[64+lane]  = scale4(f1, inv);
    p4[128+lane] = scale4(f2, inv);
    p4[192+lane] = scale4(f3, inv);
    __syncthreads();
    int tid = threadIdx.x;
    const float4* pp = (const float4*)part;
    float4 s = add4(add4(pp[tid], pp[256+tid]), add4(pp[512+tid], pp[768+tid]));
    ((float4*)Qpart)[(size_t)(e*32+g)*256 + tid] = s;
}

// ---------- K1b: combine 32 partials per e, normalize -> Q ----------
__global__ void k1b(const float* __restrict__ Qpart, float* __restrict__ Q) {
    int e = blockIdx.x, tid = threadIdx.x;
    __shared__ float red[4];
    const float4* qp = (const float4*)Qpart;
    float4 s = make_float4(0.f,0.f,0.f,0.f);
    #pragma unroll 4
    for (int g = 0; g < 32; ++g) s = add4(s, qp[(size_t)(e*32+g)*256 + tid]);
    float ss = block_sum(dot4(s,s), red);
    float inv = 1.f / fmaxf(sqrtf(ss), 1e-12f);
    ((float4*)Q)[e*256 + tid] = scale4(s, inv);
}

// ---------- K2: wave-per-row sims; writes S[i][e], S_T[e][i], InvN[i] ----------
// grid 25000 blocks, 4 waves = 4 rows per block
__global__ void k2_sim(const float* __restrict__ Bse, const float* __restrict__ Q,
                       float* __restrict__ S, float* __restrict__ ST,
                       float* __restrict__ InvN) {
    __shared__ float q_sh[NE * DIM];   // 32 KB
    int tid = threadIdx.x, wv = tid >> 6, lane = tid & 63;
    {
        const float4* Q4 = (const float4*)Q;
        float4* q4 = (float4*)q_sh;
        #pragma unroll
        for (int k = 0; k < 8; ++k) q4[k*256 + tid] = Q4[k*256 + tid];
    }
    __syncthreads();
    const float4* q4 = (const float4*)q_sh;
    size_t i = (size_t)blockIdx.x * 4 + wv;
    const float4* b4 = (const float4*)(Bse + i * DIM);
    float4 b0 = b4[lane], b1 = b4[64+lane], b2 = b4[128+lane], b3 = b4[192+lane];
    float pv[9];
    pv[8] = dot4(b0,b0) + dot4(b1,b1) + dot4(b2,b2) + dot4(b3,b3);
    #pragma unroll
    for (int e = 0; e < NE; ++e) {
        float4 q0 = q4[e*256+lane],     q1 = q4[e*256+64+lane];
        float4 q2 = q4[e*256+128+lane], q3 = q4[e*256+192+lane];
        pv[e] = dot4(b0,q0) + dot4(b1,q1) + dot4(b2,q2) + dot4(b3,q3);
    }
    #pragma unroll
    for (int v = 0; v < 9; ++v) pv[v] = wave_sum_xor(pv[v]);
    float invn = 1.f / fmaxf(sqrtf(pv[8]), 1e-12f);
    if (lane < 8) {
        float v = pv[0];
        #pragma unroll
        for (int e = 1; e < 8; ++e) v = (lane == e) ? pv[e] : v;
        float sv = v * invn;
        S[i*NE + lane] = sv;
        ST[(size_t)lane*NBASE + i] = sv;
    }
    if (lane == 0) InvN[i] = invn;
}

// ---------- K3a: per-e 4096-bin histogram (parallel, coalesced over S_T) ----------
// grid 256 = NE*32
__global__ void k3a(const float* __restrict__ ST, int* __restrict__ Hist) {
    int e = blockIdx.x >> 5, chunk = blockIdx.x & 31;
    __shared__ int h[NB1];
    for (int b = threadIdx.x; b < NB1; b += 256) h[b] = 0;
    __syncthreads();
    const int per = (NBASE + 31) / 32;
    int i0 = chunk * per, i1 = min(i0 + per, NBASE);
    for (int i = i0 + threadIdx.x; i < i1; i += 256) {
        float s = ST[(size_t)e*NBASE + i];
        atomicAdd(&h[bin1(s)], 1);
    }
    __syncthreads();
    for (int b = threadIdx.x; b < NB1; b += 256)
        if (h[b]) atomicAdd(&Hist[e*NB1 + b], h[b]);
}

// ---------- K3b: find boundary bin B and need1 per e ----------
__global__ void k3b(const int* __restrict__ Hist, int* __restrict__ Meta) {
    int e = blockIdx.x, tid = threadIdx.x;
    __shared__ int gsum[256];
    int s = 0;
    #pragma unroll
    for (int j = 0; j < 16; ++j) s += Hist[e*NB1 + tid*16 + j];
    gsum[tid] = s;
    __syncthreads();
    if (tid == 0) {
        int cum = 0;
        for (int g = 255; g >= 0; --g) {
            if (cum + gsum[g] >= KSEL) {
                for (int b = g*16 + 15;; --b) {
                    int c = Hist[e*NB1 + b];
                    if (cum + c >= KSEL) { Meta[e*4+0] = b; Meta[e*4+1] = KSEL - cum; break; }
                    cum += c;
                }
                break;
            }
            cum += gsum[g];
        }
    }
}

// ---------- K3c: 256-sub-bin histogram of boundary bin ----------
__global__ void k3c(const float* __restrict__ ST, const int* __restrict__ Meta,
                    int* __restrict__ SubHist) {
    int e = blockIdx.x >> 5, chunk = blockIdx.x & 31;
    int B = Meta[e*4];
    __shared__ int h[256];
    h[threadIdx.x] = 0;
    __syncthreads();
    const int per = (NBASE + 31) / 32;
    int i0 = chunk * per, i1 = min(i0 + per, NBASE);
    for (int i = i0 + threadIdx.x; i < i1; i += 256) {
        float s = ST[(size_t)e*NBASE + i];
        if (bin1(s) == B) atomicAdd(&h[bin2(s, B)], 1);
    }
    __syncthreads();
    if (h[threadIdx.x]) atomicAdd(&SubHist[e*256 + threadIdx.x], h[threadIdx.x]);
}

// ---------- K3d: find sub-bin B2 and need2 per e ----------
__global__ void k3d(const int* __restrict__ SubHist, int* __restrict__ Meta) {
    int e = blockIdx.x;
    if (threadIdx.x != 0) return;
    int need1 = Meta[e*4+1], cum = 0;
    for (int b = 255; b >= 0; --b) {
        int c = SubHist[e*256 + b];
        if (cum + c >= need1) { Meta[e*4+2] = b; Meta[e*4+3] = need1 - cum; return; }
        cum += c;
    }
    Meta[e*4+2] = 0; Meta[e*4+3] = need1 - cum;
}

// ---------- K3e: flags pass (1 thread per row, all 8 e) + boundary candidates ----------
__global__ void k3e(const float* __restrict__ S, const int* __restrict__ Meta,
                    unsigned char* __restrict__ Flags, int* __restrict__ CandI,
                    float* __restrict__ CandV, int* __restrict__ CandCnt) {
    int i = blockIdx.x * 256 + threadIdx.x;
    if (i >= NBASE) return;
    const float4* S4 = (const float4*)S;
    float4 sa = S4[(size_t)i*2], sb = S4[(size_t)i*2 + 1];
    float sv[8] = {sa.x, sa.y, sa.z, sa.w, sb.x, sb.y, sb.z, sb.w};
    unsigned long long flw = 0ull;
    #pragma unroll
    for (int e = 0; e < 8; ++e) {
        int B = Meta[e*4], B2 = Meta[e*4+2];
        int b = bin1(sv[e]);
        int fl = 0;
        if (b > B) fl = 1;
        else if (b == B) {
            int b2 = bin2(sv[e], B);
            if (b2 > B2) fl = 1;
            else if (b2 == B2) {
                int k = atomicAdd(&CandCnt[e], 1);
                if (k < CAP2) { CandI[e*CAP2 + k] = i; CandV[e*CAP2 + k] = sv[e]; }
            }
        }
        flw |= ((unsigned long long)fl) << (8*e);
    }
    *(unsigned long long*)(Flags + (size_t)i * 8) = flw;
}

// ---------- K3f: pick need2 winners in boundary sub-bin (value desc, idx asc) ----------
__global__ void k3f(const int* __restrict__ Meta, const int* __restrict__ CandCnt,
                    int* __restrict__ CandI, const float* __restrict__ CandV,
                    unsigned char* __restrict__ Flags) {
    int e = blockIdx.x;
    if (threadIdx.x != 0) return;
    int need2 = Meta[e*4+3];
    int n = min(CandCnt[e], CAP2);
    for (int t = 0; t < need2; ++t) {
        int best = -1, bi = 0; float bv = 0.f;
        for (int j = 0; j < n; ++j) {
            int ij = CandI[e*CAP2 + j];
            if (ij < 0) continue;
            float vj = CandV[e*CAP2 + j];
            if (best < 0 || vj > bv || (vj == bv && ij < bi)) { best = j; bv = vj; bi = ij; }
        }
        if (best < 0) break;
        Flags[(size_t)bi * NE + e] = 1;
        CandI[e*CAP2 + best] = -1;
    }
}

// ---------- K3g: compact selected rows -> (SelIdx, Coef[8]) list ----------
// One thread per row. Wave-level ballot + prefix, one atomicAdd per wave.
__global__ void k3g(const float* __restrict__ S, const float* __restrict__ InvN,
                    const unsigned char* __restrict__ Flags,
                    int* __restrict__ SelIdx, float* __restrict__ Coef,
                    int* __restrict__ SelCnt) {
    int i = blockIdx.x * 256 + threadIdx.x;
    int lane = threadIdx.x & 63;
    unsigned long long fl = 0ull;
    bool act = false;
    if (i < NBASE) {
        fl = *(const unsigned long long*)(Flags + (size_t)i * 8);
        act = (fl != 0ull);
    }
    unsigned long long ball = __ballot(act);
    int total = __popcll(ball);
    int prefix = __popcll(ball & ((1ull << lane) - 1ull));
    int base = 0;
    if (lane == 0 && total) base = atomicAdd(SelCnt, total);
    base = __shfl(base, 0, 64);
    if (act) {
        int slot = base + prefix;
        SelIdx[slot] = i;
        float inv = InvN[i];
        const float4* S4 = (const float4*)S;
        float4 sa = S4[(size_t)i*2], sb = S4[(size_t)i*2 + 1];
        float sv[8] = {sa.x, sa.y, sa.z, sa.w, sb.x, sb.y, sb.z, sb.w};
        float cf[8];
        #pragma unroll
        for (int e = 0; e < 8; ++e)
            cf[e] = ((fl >> (8*e)) & 0xffull) ? sqrtf(fmaxf(sv[e], 0.f)) * inv : 0.f;
        float4* C4 = (float4*)(Coef + (size_t)slot * 8);
        C4[0] = make_float4(cf[0], cf[1], cf[2], cf[3]);
        C4[1] = make_float4(cf[4], cf[5], cf[6], cf[7]);
    }
}

// ---------- K4: weighted accumulate over COMPACTED list -> per-block partials ----------
// Contiguous chunk per block (SelIdx ~ascending -> near-sequential Bse reads);
// 4-row unroll gives 4 independent float4 loads in flight per wave (MLP);
// coef/idx loads are wave-uniform -> scalar loads.
__global__ void k4_part(const float* __restrict__ Bse, const int* __restrict__ SelIdx,
                        const float* __restrict__ Coef, const int* __restrict__ SelCnt,
                        float* __restrict__ Part) {
    int tid = threadIdx.x;
    int n = *SelCnt;
    int G = gridDim.x;
    int per = (n + G - 1) / G;
    int j0 = min(blockIdx.x * per, n);
    int j1 = min(j0 + per, n);
    float acc[NE][4];
    #pragma unroll
    for (int e = 0; e < NE; ++e)
        #pragma unroll
        for (int q = 0; q < 4; ++q) acc[e][q] = 0.f;

    int j = j0;
    for (; j + 4 <= j1; j += 4) {
        int ia = SelIdx[j], ib2 = SelIdx[j+1], ic = SelIdx[j+2], id = SelIdx[j+3];
        // 4 independent row loads issued back-to-back (4 KB in flight per wave)
        float4 b0 = ((const float4*)(Bse + (size_t)ia  * DIM))[tid];
        float4 b1 = ((const float4*)(Bse + (size_t)ib2 * DIM))[tid];
        float4 b2 = ((const float4*)(Bse + (size_t)ic  * DIM))[tid];
        float4 b3 = ((const float4*)(Bse + (size_t)id  * DIM))[tid];
        const float4* cf4 = (const float4*)(Coef + (size_t)j * 8);
        float4 cA0 = cf4[0], cA1 = cf4[1], cB0 = cf4[2], cB1 = cf4[3];
        float4 cC0 = cf4[4], cC1 = cf4[5], cD0 = cf4[6], cD1 = cf4[7];
        float cA[8] = {cA0.x,cA0.y,cA0.z,cA0.w,cA1.x,cA1.y,cA1.z,cA1.w};
        float cB[8] = {cB0.x,cB0.y,cB0.z,cB0.w,cB1.x,cB1.y,cB1.z,cB1.w};
        float cC[8] = {cC0.x,cC0.y,cC0.z,cC0.w,cC1.x,cC1.y,cC1.z,cC1.w};
        float cD[8] = {cD0.x,cD0.y,cD0.z,cD0.w,cD1.x,cD1.y,cD1.z,cD1.w};
        fma_row(acc, cA, b0);
        fma_row(acc, cB, b1);
        fma_row(acc, cC, b2);
        fma_row(acc, cD, b3);
    }
    for (; j < j1; ++j) {
        int idx = SelIdx[j];
        const float4* cf4 = (const float4*)(Coef + (size_t)j * 8);
        float4 c0 = cf4[0], c1 = cf4[1];
        float cf[8] = {c0.x, c0.y, c0.z, c0.w, c1.x, c1.y, c1.z, c1.w};
        float4 b = ((const float4*)(Bse + (size_t)idx * DIM))[tid];
        fma_row(acc, cf, b);
    }

    float4* P4 = (float4*)Part;
    #pragma unroll
    for (int e = 0; e < NE; ++e)
        P4[(size_t)blockIdx.x*2048 + e*256 + tid] =
            make_float4(acc[e][0], acc[e][1], acc[e][2], acc[e][3]);
}

// fallback when ws is too small for partials
__global__ void k4_atomic(const float* __restrict__ Bse, const int* __restrict__ SelIdx,
                          const float* __restrict__ Coef, const int* __restrict__ SelCnt,
                          float* __restrict__ Acc) {
    int tid = threadIdx.x;
    int n = *SelCnt;
    int G = gridDim.x;
    int per = (n + G - 1) / G;
    int j0 = min(blockIdx.x * per, n);
    int j1 = min(j0 + per, n);
    float acc[NE][4];
    #pragma unroll
    for (int e = 0; e < NE; ++e)
        #pragma unroll
        for (int q = 0; q < 4; ++q) acc[e][q] = 0.f;
    for (int j = j0; j < j1; ++j) {
        int idx = SelIdx[j];
        const float4* cf4 = (const float4*)(Coef + (size_t)j * 8);
        float4 c0 = cf4[0], c1 = cf4[1];
        float cf[8] = {c0.x, c0.y, c0.z, c0.w, c1.x, c1.y, c1.z, c1.w};
        float4 b = ((const float4*)(Bse + (size_t)idx * DIM))[tid];
        fma_row(acc, cf, b);
    }
    #pragma unroll
    for (int e = 0; e < NE; ++e)
        #pragma unroll
        for (int q = 0; q < 4; ++q)
            atomicAdd(&Acc[e*DIM + tid*4 + q], acc[e][q]);
}

// ---------- K4b: reduce partials (32 slices per output chunk) ----------
__global__ void k4b(const float* __restrict__ Part, float* __restrict__ Acc, int nparts) {
    int g = blockIdx.x * 256 + threadIdx.x;   // 65536 threads
    int c = g & 2047, s = g >> 11;            // 32 slices
    const float4* P4 = (const float4*)Part;
    float4 a = make_float4(0.f,0.f,0.f,0.f);
    for (int b = s; b < nparts; b += 32) a = add4(a, P4[(size_t)b*2048 + c]);
    atomicAdd(&Acc[c*4+0], a.x);
    atomicAdd(&Acc[c*4+1], a.y);
    atomicAdd(&Acc[c*4+2], a.z);
    atomicAdd(&Acc[c*4+3], a.w);
}

// ---------- K5: A = normalize(Acc) ----------
__global__ void k5(const float* __restrict__ Acc, float* __restrict__ A) {
    int e = blockIdx.x, tid = threadIdx.x;
    __shared__ float red[4];
    float4 a = ((const float4*)Acc)[e*256 + tid];
    float ss = block_sum(dot4(a,a), red);
    float inv = 1.f / fmaxf(sqrtf(ss), 1e-12f);
    ((float4*)A)[e*256 + tid] = scale4(a, inv);
}

// ---------- K6: out = normalize(fn - (fn.a) a), wave-per-row ----------
__global__ void k6(const float* __restrict__ F, const float* __restrict__ A,
                   float* __restrict__ Out) {
    int wv = threadIdx.x >> 6, lane = threadIdx.x & 63;
    size_t rid = (size_t)blockIdx.x * 4 + wv;
    int e = (int)(rid >> 10);
    const float4* f4 = (const float4*)(F + rid * DIM);
    const float4* a4 = (const float4*)(A + (size_t)e * DIM);
    float4 f0 = f4[lane], f1 = f4[64+lane], f2 = f4[128+lane], f3 = f4[192+lane];
    float4 a0 = a4[lane], a1 = a4[64+lane], a2 = a4[128+lane], a3 = a4[192+lane];
    float ss = dot4(f0,f0) + dot4(f1,f1) + dot4(f2,f2) + dot4(f3,f3);
    ss = wave_sum_xor(ss);
    float invf = 1.f / fmaxf(sqrtf(ss), 1e-12f);
    f0 = scale4(f0, invf); f1 = scale4(f1, invf); f2 = scale4(f2, invf); f3 = scale4(f3, invf);
    float c = dot4(f0,a0) + dot4(f1,a1) + dot4(f2,a2) + dot4(f3,a3);
    c = wave_sum_xor(c);
    float4 r0 = make_float4(f0.x - c*a0.x, f0.y - c*a0.y, f0.z - c*a0.z, f0.w - c*a0.w);
    float4 r1 = make_float4(f1.x - c*a1.x, f1.y - c*a1.y, f1.z - c*a1.z, f1.w - c*a1.w);
    float4 r2 = make_float4(f2.x - c*a2.x, f2.y - c*a2.y, f2.z - c*a2.z, f2.w - c*a2.w);
    float4 r3 = make_float4(f3.x - c*a3.x, f3.y - c*a3.y, f3.z - c*a3.z, f3.w - c*a3.w);
    float rs = dot4(r0,r0) + dot4(r1,r1) + dot4(r2,r2) + dot4(r3,r3);
    rs = wave_sum_xor(rs);
    float invr = 1.f / fmaxf(sqrtf(rs), 1e-12f);
    float4* o4 = (float4*)(Out + rid * DIM);
    o4[lane]     = scale4(r0, invr);
    o4[64+lane]  = scale4(r1, invr);
    o4[128+lane] = scale4(r2, invr);
    o4[192+lane] = scale4(r3, invr);
}

extern "C" void kernel_launch(void* const* d_in, const int* in_sizes, int n_in,
                              void* d_out, int out_size, void* d_ws, size_t ws_size,
                              hipStream_t stream) {
    const float* F   = (const float*)d_in[0];   // (8,1024,1024)
    const float* Bse = (const float*)d_in[1];   // (100000,1024)
    float* Out = (float*)d_out;

    char* ws = (char*)d_ws;
    size_t off = 0;
    auto alloc = [&](size_t bytes) -> void* {
        void* p = ws + off;
        off += (bytes + 255) & ~(size_t)255;
        return p;
    };
    float* Q     = (float*)alloc((size_t)NE * DIM * 4);
    float* Qpart = (float*)alloc((size_t)NE * 32 * DIM * 4);       // 1 MB
    float* S     = (float*)alloc((size_t)NBASE * NE * 4);          // 3.2 MB
    float* ST    = (float*)alloc((size_t)NE * NBASE * 4);          // 3.2 MB
    float* InvN  = (float*)alloc((size_t)NBASE * 4);               // 0.4 MB
    unsigned char* Flags = (unsigned char*)alloc((size_t)NBASE * NE); // 0.8 MB
    int*   Zero  = (int*)alloc((size_t)(NE*NB1 + NE*256 + NE + 1) * 4); // Hist+SubHist+CandCnt+SelCnt
    int*   Hist    = Zero;
    int*   SubHist = Zero + NE*NB1;
    int*   CandCnt = Zero + NE*NB1 + NE*256;
    int*   SelCnt  = Zero + NE*NB1 + NE*256 + NE;
    int*   Meta  = (int*)alloc((size_t)NE * 4 * 4);
    int*   CandI = (int*)alloc((size_t)NE * CAP2 * 4);
    float* CandV = (float*)alloc((size_t)NE * CAP2 * 4);
    float* Acc   = (float*)alloc((size_t)NE * DIM * 4);
    float* A     = (float*)alloc((size_t)NE * DIM * 4);
    int*   SelIdx = (int*)alloc((size_t)NBASE * 4);                // 0.4 MB
    float* Coef   = (float*)alloc((size_t)NBASE * 8 * 4);          // 3.2 MB

    // Part buffer: 1024 blocks is enough MLP with the 4-row unroll, and
    // halves k4b traffic vs 2048.
    int nparts = 0;
    float* Part = nullptr;
    size_t perPart = (size_t)NE * DIM * 4;   // 32 KB per block
    for (int cand : {1024, 512, 256}) {
        if (ws_size >= off + (size_t)cand * perPart) {
            nparts = cand;
            Part = (float*)alloc((size_t)cand * perPart);
            break;
        }
    }

    hipMemsetAsync(Zero, 0, (size_t)(NE*NB1 + NE*256 + NE + 1) * 4, stream);
    hipMemsetAsync(Acc, 0, (size_t)NE * DIM * 4, stream);

    k1a<<<NE*32, 256, 0, stream>>>(F, Qpart);
    k1b<<<NE, 256, 0, stream>>>(Qpart, Q);
    k2_sim<<<(NBASE+3)/4, 256, 0, stream>>>(Bse, Q, S, ST, InvN);
    k3a<<<NE*32, 256, 0, stream>>>(ST, Hist);
    k3b<<<NE, 256, 0, stream>>>(Hist, Meta);
    k3c<<<NE*32, 256, 0, stream>>>(ST, Meta, SubHist);
    k3d<<<NE, 64, 0, stream>>>(SubHist, Meta);
    k3e<<<(NBASE+255)/256, 256, 0, stream>>>(S, Meta, Flags, CandI, CandV, CandCnt);
    k3f<<<NE, 64, 0, stream>>>(Meta, CandCnt, CandI, CandV, Flags);
    k3g<<<(NBASE+255)/256, 256, 0, stream>>>(S, InvN, Flags, SelIdx, Coef, SelCnt);
    if (nparts) {
        k4_part<<<nparts, 256, 0, stream>>>(Bse, SelIdx, Coef, SelCnt, Part);
        k4b<<<256, 256, 0, stream>>>(Part, Acc, nparts);
    } else {
        k4_atomic<<<512, 256, 0, stream>>>(Bse, SelIdx, Coef, SelCnt, Acc);
    }
    k5<<<NE, 256, 0, stream>>>(Acc, A);
    k6<<<(NE*1024)/4, 256, 0, stream>>>(F, A, Out);
}